// Round 2
// baseline (755.522 us; speedup 1.0000x reference)
//
#include <hip/hip_runtime.h>
#include <hip/hip_bf16.h>

// Problem constants: N=64 batch, C=23 chromosomes, G=20000 genes, H=64 hidden.
// x:(N,G,H) f32, chrom_mat:(C,G) one-hot f32, attention:(C,H) f32. out:(N,C,H) f32.
#define N_ 64
#define C_ 23
#define G_ 20000
#define H_ 64
#define SLICES 32                       // gene slices per batch item
#define GPB ((G_ + SLICES - 1) / SLICES)  // genes per block = 625

// ---------------------------------------------------------------------------
// Kernel 1: recover assign[g] = index of the nonzero in one-hot chrom_mat[:,g].
// Coalesced: fixed c, consecutive g across lanes. No atomics needed.
__global__ void assign_kernel(const float* __restrict__ chrom,
                              int* __restrict__ assign) {
    int g = blockIdx.x * blockDim.x + threadIdx.x;
    if (g >= G_) return;
    int c_found = 0;
    #pragma unroll
    for (int c = 0; c < C_; ++c) {
        if (chrom[c * G_ + g] != 0.f) c_found = c;
    }
    assign[g] = c_found;
}

// ---------------------------------------------------------------------------
// Kernel 2 (main): block = (n, contiguous gene slice). x is read as a pure
// linear stream (consecutive genes -> consecutive 256B rows; a wave's 4
// gene-groups cover 1KB contiguous). All 23 chromosome accumulators live in
// LDS; hardware ds_add_f32 atomics (unsafeAtomicAdd). One global atomic
// flush per block at the end.
__global__ __launch_bounds__(256) void main_stream(
    const float* __restrict__ x,        // (N,G,H)
    const float* __restrict__ attn,     // (C,H)
    const int* __restrict__ assign,     // (G)
    float* __restrict__ acc,            // (N,C,H)  zero-initialized
    float* __restrict__ denom)          // (N,C)    zero-initialized
{
    __shared__ float attn_s[C_ * H_];
    __shared__ float acc_s[C_ * H_];
    __shared__ float den_s[C_];

    int n = blockIdx.x / SLICES;
    int s = blockIdx.x % SLICES;
    int lo = s * GPB;
    int hi = min(lo + GPB, G_);

    int tid = threadIdx.x;
    for (int i = tid; i < C_ * H_; i += 256) {
        attn_s[i] = attn[i];
        acc_s[i]  = 0.f;
    }
    if (tid < C_) den_s[tid] = 0.f;
    __syncthreads();

    int sub = tid & 15;   // lane within 16-lane gene group: h = 4*sub..4*sub+3
    int grp = tid >> 4;   // gene group id within block, 0..15

    for (int g = lo + grp; g < hi; g += 16) {
        int c = assign[g];                                  // broadcast within group
        const float4 x4 = ((const float4*)(x + ((size_t)n * G_ + g) * H_))[sub];
        const float4 a4 = ((const float4*)(attn_s + c * H_))[sub];
        float part = a4.x * x4.x + a4.y * x4.y + a4.z * x4.z + a4.w * x4.w;
        // reduce dot over the 16 lanes of this gene group (xor stays in-group)
        part += __shfl_xor(part, 1);
        part += __shfl_xor(part, 2);
        part += __shfl_xor(part, 4);
        part += __shfl_xor(part, 8);
        // att == part (one-hot value is exactly 1.0); mask = (att != 0)
        float w = 0.f;
        if (part != 0.f) {
            float lr = (part >= 0.f) ? part : 0.2f * part;
            w = __expf(lr);
        }
        float* ap = acc_s + c * H_ + sub * 4;
        unsafeAtomicAdd(ap + 0, w * x4.x);
        unsafeAtomicAdd(ap + 1, w * x4.y);
        unsafeAtomicAdd(ap + 2, w * x4.z);
        unsafeAtomicAdd(ap + 3, w * x4.w);
        if (sub == 0) unsafeAtomicAdd(&den_s[c], w);
    }
    __syncthreads();

    // Flush block partials to global accumulators.
    float* accg = acc + (size_t)n * C_ * H_;
    for (int i = tid; i < C_ * H_; i += 256) {
        float v = acc_s[i];
        if (v != 0.f) unsafeAtomicAdd(accg + i, v);
    }
    if (tid < C_) {
        float v = den_s[tid];
        if (v != 0.f) unsafeAtomicAdd(denom + n * C_ + tid, v);
    }
}

// ---------------------------------------------------------------------------
// Kernel 3: out = acc / max(denom, 1e-10)
__global__ void finalize_kernel(const float* __restrict__ acc,
                                const float* __restrict__ denom,
                                float* __restrict__ out) {
    int i = blockIdx.x * blockDim.x + threadIdx.x;
    if (i >= N_ * C_ * H_) return;
    int nc = i >> 6;  // / H_
    float d = fmaxf(denom[nc], 1e-10f);
    out[i] = acc[i] / d;
}

// ---------------------------------------------------------------------------
extern "C" void kernel_launch(void* const* d_in, const int* in_sizes, int n_in,
                              void* d_out, int out_size, void* d_ws, size_t ws_size,
                              hipStream_t stream) {
    const float* x     = (const float*)d_in[0];   // N*G*H
    const float* chrom = (const float*)d_in[1];   // C*G
    const float* attn  = (const float*)d_in[2];   // C*H
    float* out = (float*)d_out;

    // Workspace layout:
    //   acc    : N*C*H floats   (zeroed)
    //   denom  : N*C   floats   (zeroed)
    //   assign : G     ints     (fully overwritten)
    float* acc    = (float*)d_ws;
    float* denom  = acc + (size_t)N_ * C_ * H_;
    int*   assign = (int*)(denom + (size_t)N_ * C_);

    size_t zero_bytes = ((size_t)N_ * C_ * H_ + (size_t)N_ * C_) * sizeof(float);
    hipMemsetAsync(d_ws, 0, zero_bytes, stream);

    assign_kernel<<<(G_ + 255) / 256, 256, 0, stream>>>(chrom, assign);

    main_stream<<<N_ * SLICES, 256, 0, stream>>>(x, attn, assign, acc, denom);

    finalize_kernel<<<(N_ * C_ * H_ + 255) / 256, 256, 0, stream>>>(acc, denom, out);
}